// Round 3
// baseline (2526.038 us; speedup 1.0000x reference)
//
#include <hip/hip_runtime.h>

// GCN forward: 2x (GEMM -> D^-1/2 A D^-1/2 aggregate -> +b -> ReLU) -> linear head.
// All f32. CSR-by-destination built per call (ws is re-poisoned every launch).

__global__ __launch_bounds__(256) void init_kernel(float* deg, int* cnt, int* cur, int N) {
    int i = blockIdx.x * 256 + threadIdx.x;
    if (i < N) { deg[i] = 1.0f; cnt[i] = 0; cur[i] = 0; }  // deg starts at 1 (self-loop weight)
}

__global__ __launch_bounds__(256) void deg_cnt_kernel(const int* __restrict__ col,
                                                      const float* __restrict__ w,
                                                      float* deg, int* cnt, int E) {
    int e = blockIdx.x * 256 + threadIdx.x;
    if (e < E) {
        int c = col[e];
        atomicAdd(&deg[c], w[e]);
        atomicAdd(&cnt[c], 1);
    }
}

__global__ __launch_bounds__(256) void dinv_kernel(float* deg, int N) {
    int i = blockIdx.x * 256 + threadIdx.x;
    if (i < N) deg[i] = rsqrtf(deg[i]);  // deg >= 1 always (self-loop)
}

// Single-block coarsened exclusive scan of cnt[0..N) -> off[0..N]
__global__ __launch_bounds__(1024) void scan_kernel(const int* __restrict__ cnt,
                                                    int* __restrict__ off, int N) {
    __shared__ int sm[1024];
    int t = threadIdx.x;
    int chunk = (N + 1023) >> 10;
    int b = t * chunk;
    int e = min(b + chunk, N);
    int s = 0;
    for (int i = b; i < e; i++) s += cnt[i];
    sm[t] = s;
    __syncthreads();
#pragma unroll
    for (int d = 1; d < 1024; d <<= 1) {
        int v = (t >= d) ? sm[t - d] : 0;
        __syncthreads();
        sm[t] += v;
        __syncthreads();
    }
    int run = sm[t] - s;  // exclusive prefix of this thread's chunk
    for (int i = b; i < e; i++) { off[i] = run; run += cnt[i]; }
    if (t == 1023) off[N] = sm[1023];
}

__global__ __launch_bounds__(256) void fill_kernel(const int* __restrict__ row,
                                                   const int* __restrict__ col,
                                                   const float* __restrict__ w,
                                                   const float* __restrict__ dinv,
                                                   const int* __restrict__ off, int* cur,
                                                   int* __restrict__ csr_r,
                                                   float* __restrict__ csr_n, int E) {
    int e = blockIdx.x * 256 + threadIdx.x;
    if (e >= E) return;
    int r = row[e], c = col[e];
    int pos = off[c] + atomicAdd(&cur[c], 1);
    csr_r[pos] = r;
    csr_n[pos] = dinv[r] * w[e] * dinv[c];
}

// C[M,N] = A[M,K] @ B[K,N], f32 vector GEMM. 64x64 tile, 256 threads, 4x4 per thread.
__global__ __launch_bounds__(256) void gemm_kernel(const float* __restrict__ A,
                                                   const float* __restrict__ B,
                                                   float* __restrict__ C,
                                                   int M, int N, int K) {
    __shared__ float As[16][64];  // transposed A tile: As[k][m]
    __shared__ float Bs[16][64];  // Bs[k][n]
    int t  = threadIdx.x;
    int tx = t & 15, ty = t >> 4;
    int row0 = blockIdx.x * 64, col0 = blockIdx.y * 64;
    float acc[4][4] = {};

    int ar = t >> 2, ac = (t & 3) << 2;   // A tile load: row ar (0..63), 4 cols at ac
    int br = t >> 4, bc = (t & 15) << 2;  // B tile load: row br (0..15), 4 cols at bc
    bool aval = (row0 + ar) < M;
    const float* Ap = A + (size_t)(row0 + ar) * K + ac;
    const float* Bp = B + (size_t)br * N + col0 + bc;

    for (int k0 = 0; k0 < K; k0 += 16) {
        float4 a4 = make_float4(0.f, 0.f, 0.f, 0.f);
        if (aval) a4 = *(const float4*)(Ap + k0);
        float4 b4 = *(const float4*)(Bp + (size_t)k0 * N);
        As[ac + 0][ar] = a4.x; As[ac + 1][ar] = a4.y;
        As[ac + 2][ar] = a4.z; As[ac + 3][ar] = a4.w;
        *(float4*)&Bs[br][bc] = b4;
        __syncthreads();
#pragma unroll
        for (int k = 0; k < 16; k++) {
            float4 av = *(const float4*)&As[k][ty << 2];
            float4 bv = *(const float4*)&Bs[k][tx << 2];
            acc[0][0] += av.x * bv.x; acc[0][1] += av.x * bv.y; acc[0][2] += av.x * bv.z; acc[0][3] += av.x * bv.w;
            acc[1][0] += av.y * bv.x; acc[1][1] += av.y * bv.y; acc[1][2] += av.y * bv.z; acc[1][3] += av.y * bv.w;
            acc[2][0] += av.z * bv.x; acc[2][1] += av.z * bv.y; acc[2][2] += av.z * bv.z; acc[2][3] += av.z * bv.w;
            acc[3][0] += av.w * bv.x; acc[3][1] += av.w * bv.y; acc[3][2] += av.w * bv.z; acc[3][3] += av.w * bv.w;
        }
        __syncthreads();
    }
#pragma unroll
    for (int i = 0; i < 4; i++) {
        int r = row0 + (ty << 2) + i;
        if (r < M)
            *(float4*)&C[(size_t)r * N + col0 + (tx << 2)] =
                make_float4(acc[i][0], acc[i][1], acc[i][2], acc[i][3]);
    }
}

// One wave per node: out[n] = ReLU( sum_e norm_e * h[row_e] + dinv[n]^2 * h[n] + b )
// D = 256 floats per row; lane handles 4 (float4).
__global__ __launch_bounds__(256) void agg_kernel(const float* __restrict__ h,
                                                  const int* __restrict__ csr_r,
                                                  const float* __restrict__ csr_n,
                                                  const int* __restrict__ off,
                                                  const float* __restrict__ dinv,
                                                  const float* __restrict__ bias,
                                                  float* __restrict__ out, int N, int relu) {
    int lane = threadIdx.x & 63;
    int n = blockIdx.x * 4 + (threadIdx.x >> 6);
    if (n >= N) return;
    n = __builtin_amdgcn_readfirstlane(n);
    int start = off[n], end = off[n + 1];
    float d = dinv[n];
    const float4* hv = (const float4*)h;
    float4 self = hv[(size_t)n * 64 + lane];
    float sw = d * d;
    float ax = sw * self.x, ay = sw * self.y, az = sw * self.z, aw = sw * self.w;
    int j = start;
    for (; j + 4 <= end; j += 4) {
        int r0 = csr_r[j], r1 = csr_r[j + 1], r2 = csr_r[j + 2], r3 = csr_r[j + 3];
        float n0 = csr_n[j], n1 = csr_n[j + 1], n2 = csr_n[j + 2], n3 = csr_n[j + 3];
        float4 h0 = hv[(size_t)r0 * 64 + lane];
        float4 h1 = hv[(size_t)r1 * 64 + lane];
        float4 h2 = hv[(size_t)r2 * 64 + lane];
        float4 h3 = hv[(size_t)r3 * 64 + lane];
        ax += n0 * h0.x + n1 * h1.x + n2 * h2.x + n3 * h3.x;
        ay += n0 * h0.y + n1 * h1.y + n2 * h2.y + n3 * h3.y;
        az += n0 * h0.z + n1 * h1.z + n2 * h2.z + n3 * h3.z;
        aw += n0 * h0.w + n1 * h1.w + n2 * h2.w + n3 * h3.w;
    }
    for (; j < end; j++) {
        int r = csr_r[j];
        float nm = csr_n[j];
        float4 hr = hv[(size_t)r * 64 + lane];
        ax += nm * hr.x; ay += nm * hr.y; az += nm * hr.z; aw += nm * hr.w;
    }
    float4 b = ((const float4*)bias)[lane];
    ax += b.x; ay += b.y; az += b.z; aw += b.w;
    if (relu) {
        ax = fmaxf(ax, 0.f); ay = fmaxf(ay, 0.f);
        az = fmaxf(az, 0.f); aw = fmaxf(aw, 0.f);
    }
    ((float4*)out)[(size_t)n * 64 + lane] = make_float4(ax, ay, az, aw);
}

// out[n,c] = h[n,:] @ Wc[:,c] + bc[c], c < 10. One wave per node, shuffle reduce.
__global__ __launch_bounds__(256) void cls_kernel(const float* __restrict__ h,
                                                  const float* __restrict__ Wc,
                                                  const float* __restrict__ bc,
                                                  float* __restrict__ out, int N) {
    __shared__ float Ws[256 * 10];
    for (int i = threadIdx.x; i < 2560; i += 256) Ws[i] = Wc[i];
    __syncthreads();
    int lane = threadIdx.x & 63;
    int n = blockIdx.x * 4 + (threadIdx.x >> 6);
    if (n >= N) return;
    float4 hv4 = ((const float4*)h)[(size_t)n * 64 + lane];
    float s[10];
#pragma unroll
    for (int c = 0; c < 10; c++) {
        float v = hv4.x * Ws[(4 * lane + 0) * 10 + c] + hv4.y * Ws[(4 * lane + 1) * 10 + c] +
                  hv4.z * Ws[(4 * lane + 2) * 10 + c] + hv4.w * Ws[(4 * lane + 3) * 10 + c];
#pragma unroll
        for (int m = 32; m; m >>= 1) v += __shfl_xor(v, m, 64);
        s[c] = v;
    }
    float outv = 0.0f;
#pragma unroll
    for (int c = 0; c < 10; c++)
        if (lane == c) outv = s[c] + bc[c];
    if (lane < 10) out[(size_t)n * 10 + lane] = outv;
}

extern "C" void kernel_launch(void* const* d_in, const int* in_sizes, int n_in,
                              void* d_out, int out_size, void* d_ws, size_t ws_size,
                              hipStream_t stream) {
    const float* x  = (const float*)d_in[0];
    const int*   ei = (const int*)d_in[1];
    const float* ew = (const float*)d_in[2];
    const float* W1 = (const float*)d_in[3];
    const float* b1 = (const float*)d_in[4];
    const float* W2 = (const float*)d_in[5];
    const float* b2 = (const float*)d_in[6];
    const float* Wc = (const float*)d_in[7];
    const float* bc = (const float*)d_in[8];
    float* out = (float*)d_out;

    const int E = in_sizes[1] / 2;
    const int F = 512, D = 256;
    const int N = in_sizes[0] / F;
    const int* row = ei;
    const int* col = ei + E;

    char* ws = (char*)d_ws;
    size_t p = 0;
    auto alloc = [&](size_t bytes) -> char* {
        char* r = ws + p;
        p += (bytes + 255) & ~(size_t)255;
        return r;
    };
    float* deg   = (float*)alloc((size_t)N * 4);        // becomes dinv in place
    int*   off   = (int*)alloc((size_t)(N + 1) * 4);
    int*   cnt   = (int*)alloc((size_t)N * 4);
    int*   cur   = (int*)alloc((size_t)N * 4);
    int*   csr_r = (int*)alloc((size_t)E * 4);
    float* csr_n = (float*)alloc((size_t)E * 4);
    float* h     = (float*)alloc((size_t)N * D * 4);
    float* agg   = (float*)alloc((size_t)N * D * 4);
    (void)ws_size;

    init_kernel<<<(N + 255) / 256, 256, 0, stream>>>(deg, cnt, cur, N);
    deg_cnt_kernel<<<(E + 255) / 256, 256, 0, stream>>>(col, ew, deg, cnt, E);
    dinv_kernel<<<(N + 255) / 256, 256, 0, stream>>>(deg, N);
    scan_kernel<<<1, 1024, 0, stream>>>(cnt, off, N);
    fill_kernel<<<(E + 255) / 256, 256, 0, stream>>>(row, col, ew, deg, off, cur, csr_r, csr_n, E);

    dim3 gg((N + 63) / 64, D / 64);
    // layer 1: h = x @ W1 ; agg = ReLU(A_hat h + b1)
    gemm_kernel<<<gg, 256, 0, stream>>>(x, W1, h, N, D, F);
    agg_kernel<<<(N + 3) / 4, 256, 0, stream>>>(h, csr_r, csr_n, off, deg, b1, agg, N, 1);
    // layer 2: h = agg @ W2 ; agg = ReLU(A_hat h + b2)
    gemm_kernel<<<gg, 256, 0, stream>>>(agg, W2, h, N, D, D);
    agg_kernel<<<(N + 3) / 4, 256, 0, stream>>>(h, csr_r, csr_n, off, deg, b2, agg, N, 1);
    // classifier
    cls_kernel<<<(N + 3) / 4, 256, 0, stream>>>(agg, Wc, bc, out, N);
}

// Round 5
// 2380.763 us; speedup vs baseline: 1.0610x; 1.0610x over previous
//
#include <hip/hip_runtime.h>

// GCN forward: 2x (split-f16 MFMA GEMM -> D^-1/2 A D^-1/2 aggregate -> +b -> ReLU) -> linear head.
// GEMM: C = A@B with A,B split as hi+lo f16; 3 MFMA products give ~1e-5 rel error.
// B pre-packed into k-panels [K/8][256][8] f16 so fragment loads are coalesced b128 from L2.
// A streams global->VGPR (no LDS: no cross-wave A reuse at BM=64/4 waves, B is L2-resident).

typedef __attribute__((ext_vector_type(8))) _Float16 f16x8;
typedef __attribute__((ext_vector_type(4))) float f32x4;

__global__ __launch_bounds__(256) void init_kernel(float* deg, int* cnt, int* cur, int N) {
    int i = blockIdx.x * 256 + threadIdx.x;
    if (i < N) { deg[i] = 1.0f; cnt[i] = 0; cur[i] = 0; }  // deg starts at 1 (self-loop weight)
}

__global__ __launch_bounds__(256) void deg_cnt_kernel(const int* __restrict__ col,
                                                      const float* __restrict__ w,
                                                      float* deg, int* cnt, int E) {
    int e = blockIdx.x * 256 + threadIdx.x;
    if (e < E) {
        int c = col[e];
        atomicAdd(&deg[c], w[e]);
        atomicAdd(&cnt[c], 1);
    }
}

__global__ __launch_bounds__(256) void dinv_kernel(float* deg, int N) {
    int i = blockIdx.x * 256 + threadIdx.x;
    if (i < N) deg[i] = rsqrtf(deg[i]);  // deg >= 1 always (self-loop)
}

// Single-block coarsened exclusive scan of cnt[0..N) -> off[0..N]
__global__ __launch_bounds__(1024) void scan_kernel(const int* __restrict__ cnt,
                                                    int* __restrict__ off, int N) {
    __shared__ int sm[1024];
    int t = threadIdx.x;
    int chunk = (N + 1023) >> 10;
    int b = t * chunk;
    int e = min(b + chunk, N);
    int s = 0;
    for (int i = b; i < e; i++) s += cnt[i];
    sm[t] = s;
    __syncthreads();
#pragma unroll
    for (int d = 1; d < 1024; d <<= 1) {
        int v = (t >= d) ? sm[t - d] : 0;
        __syncthreads();
        sm[t] += v;
        __syncthreads();
    }
    int run = sm[t] - s;  // exclusive prefix of this thread's chunk
    for (int i = b; i < e; i++) { off[i] = run; run += cnt[i]; }
    if (t == 1023) off[N] = sm[1023];
}

__global__ __launch_bounds__(256) void fill_kernel(const int* __restrict__ row,
                                                   const int* __restrict__ col,
                                                   const float* __restrict__ w,
                                                   const float* __restrict__ dinv,
                                                   const int* __restrict__ off, int* cur,
                                                   int* __restrict__ csr_r,
                                                   float* __restrict__ csr_n, int E) {
    int e = blockIdx.x * 256 + threadIdx.x;
    if (e >= E) return;
    int r = row[e], c = col[e];
    int pos = off[c] + atomicAdd(&cur[c], 1);
    csr_r[pos] = r;
    csr_n[pos] = dinv[r] * w[e] * dinv[c];
}

// Pack B [K][256] f32 -> hi/lo f16 k-panels: Bp[k>>3][n][k&7]
__global__ __launch_bounds__(256) void prep_b_kernel(const float* __restrict__ B,
                                                     _Float16* __restrict__ Bph,
                                                     _Float16* __restrict__ Bpl, int K) {
    int e = blockIdx.x * 256 + threadIdx.x;
    if (e >= K * 256) return;
    int k = e >> 8, n = e & 255;
    float v = B[e];
    _Float16 h = (_Float16)v;
    _Float16 lo = (_Float16)(v - (float)h);
    size_t idx = ((((size_t)(k >> 3)) * 256 + n) << 3) | (k & 7);
    Bph[idx] = h;
    Bpl[idx] = lo;
}

// C[M,256] = A[M,K] @ B[K,256] via split-f16 MFMA (16x16x32).
// grid.x = ceil(M/64); 4 waves/block, each wave owns 16 rows x all 256 cols.
__global__ __launch_bounds__(256) void gemm_split_kernel(const float* __restrict__ A,
                                                         const _Float16* __restrict__ Bph,
                                                         const _Float16* __restrict__ Bpl,
                                                         float* __restrict__ C,
                                                         int M, int K) {
    int t = threadIdx.x;
    int w = t >> 6, l = t & 63;
    int lr = l & 15;   // row-within-16 (A), col-within-16 (B/C)
    int lg = l >> 4;   // k-group 0..3
    int m0 = blockIdx.x * 64 + w * 16;

    int arow = m0 + lr;
    if (arow >= M) arow = M - 1;  // clamp: reads stay in-bounds, stores guarded below
    const float* Ap = A + (size_t)arow * K + lg * 8;

    f32x4 acc[16];
#pragma unroll
    for (int i = 0; i < 16; i++) acc[i] = (f32x4)0.0f;

    const f16x8* BH = (const f16x8*)Bph;
    const f16x8* BL = (const f16x8*)Bpl;

    for (int k0 = 0; k0 < K; k0 += 64) {
#pragma unroll
        for (int ks = 0; ks < 2; ks++) {
            const float* ap = Ap + k0 + ks * 32;
            f32x4 a0 = *(const f32x4*)ap;
            f32x4 a1 = *(const f32x4*)(ap + 4);
            f16x8 ah, al;
#pragma unroll
            for (int j = 0; j < 4; j++) {
                float v = a0[j];
                _Float16 hi = (_Float16)v;
                ah[j] = hi;
                al[j] = (_Float16)(v - (float)hi);
                float v2 = a1[j];
                _Float16 hi2 = (_Float16)v2;
                ah[j + 4] = hi2;
                al[j + 4] = (_Float16)(v2 - (float)hi2);
            }
            size_t bbase = ((size_t)(((k0 + ks * 32) >> 3) + lg)) * 256 + lr;
#pragma unroll
            for (int nf = 0; nf < 16; nf++) {
                f16x8 bh = BH[bbase + nf * 16];
                f16x8 bl = BL[bbase + nf * 16];
                acc[nf] = __builtin_amdgcn_mfma_f32_16x16x32_f16(ah, bh, acc[nf], 0, 0, 0);
                acc[nf] = __builtin_amdgcn_mfma_f32_16x16x32_f16(al, bh, acc[nf], 0, 0, 0);
                acc[nf] = __builtin_amdgcn_mfma_f32_16x16x32_f16(ah, bl, acc[nf], 0, 0, 0);
            }
        }
    }
    // C/D layout (m89-verified): col = lane&15 (+16*nf), row = (lane>>4)*4 + reg
#pragma unroll
    for (int nf = 0; nf < 16; nf++) {
#pragma unroll
        for (int r = 0; r < 4; r++) {
            int row = m0 + lg * 4 + r;
            if (row < M) C[(size_t)row * 256 + nf * 16 + lr] = acc[nf][r];
        }
    }
}

// One wave per node: out[n] = ReLU( sum_e norm_e * h[row_e] + dinv[n]^2 * h[n] + b )
// D = 256 floats per row; lane handles 4 (float4).
__global__ __launch_bounds__(256) void agg_kernel(const float* __restrict__ h,
                                                  const int* __restrict__ csr_r,
                                                  const float* __restrict__ csr_n,
                                                  const int* __restrict__ off,
                                                  const float* __restrict__ dinv,
                                                  const float* __restrict__ bias,
                                                  float* __restrict__ out, int N, int relu) {
    int lane = threadIdx.x & 63;
    int n = blockIdx.x * 4 + (threadIdx.x >> 6);
    if (n >= N) return;
    n = __builtin_amdgcn_readfirstlane(n);
    int start = off[n], end = off[n + 1];
    float d = dinv[n];
    const float4* hv = (const float4*)h;
    float4 self = hv[(size_t)n * 64 + lane];
    float sw = d * d;
    float ax = sw * self.x, ay = sw * self.y, az = sw * self.z, aw = sw * self.w;
    int j = start;
    for (; j + 4 <= end; j += 4) {
        int r0 = csr_r[j], r1 = csr_r[j + 1], r2 = csr_r[j + 2], r3 = csr_r[j + 3];
        float n0 = csr_n[j], n1 = csr_n[j + 1], n2 = csr_n[j + 2], n3 = csr_n[j + 3];
        float4 h0 = hv[(size_t)r0 * 64 + lane];
        float4 h1 = hv[(size_t)r1 * 64 + lane];
        float4 h2 = hv[(size_t)r2 * 64 + lane];
        float4 h3 = hv[(size_t)r3 * 64 + lane];
        ax += n0 * h0.x + n1 * h1.x + n2 * h2.x + n3 * h3.x;
        ay += n0 * h0.y + n1 * h1.y + n2 * h2.y + n3 * h3.y;
        az += n0 * h0.z + n1 * h1.z + n2 * h2.z + n3 * h3.z;
        aw += n0 * h0.w + n1 * h1.w + n2 * h2.w + n3 * h3.w;
    }
    for (; j < end; j++) {
        int r = csr_r[j];
        float nm = csr_n[j];
        float4 hr = hv[(size_t)r * 64 + lane];
        ax += nm * hr.x; ay += nm * hr.y; az += nm * hr.z; aw += nm * hr.w;
    }
    float4 b = ((const float4*)bias)[lane];
    ax += b.x; ay += b.y; az += b.z; aw += b.w;
    if (relu) {
        ax = fmaxf(ax, 0.f); ay = fmaxf(ay, 0.f);
        az = fmaxf(az, 0.f); aw = fmaxf(aw, 0.f);
    }
    ((float4*)out)[(size_t)n * 64 + lane] = make_float4(ax, ay, az, aw);
}

// out[n,c] = h[n,:] @ Wc[:,c] + bc[c], c < 10. One wave per node, shuffle reduce.
__global__ __launch_bounds__(256) void cls_kernel(const float* __restrict__ h,
                                                  const float* __restrict__ Wc,
                                                  const float* __restrict__ bc,
                                                  float* __restrict__ out, int N) {
    __shared__ float Ws[256 * 10];
    for (int i = threadIdx.x; i < 2560; i += 256) Ws[i] = Wc[i];
    __syncthreads();
    int lane = threadIdx.x & 63;
    int n = blockIdx.x * 4 + (threadIdx.x >> 6);
    if (n >= N) return;
    float4 hv4 = ((const float4*)h)[(size_t)n * 64 + lane];
    float s[10];
#pragma unroll
    for (int c = 0; c < 10; c++) {
        float v = hv4.x * Ws[(4 * lane + 0) * 10 + c] + hv4.y * Ws[(4 * lane + 1) * 10 + c] +
                  hv4.z * Ws[(4 * lane + 2) * 10 + c] + hv4.w * Ws[(4 * lane + 3) * 10 + c];
#pragma unroll
        for (int m = 32; m; m >>= 1) v += __shfl_xor(v, m, 64);
        s[c] = v;
    }
    float outv = 0.0f;
#pragma unroll
    for (int c = 0; c < 10; c++)
        if (lane == c) outv = s[c] + bc[c];
    if (lane < 10) out[(size_t)n * 10 + lane] = outv;
}

extern "C" void kernel_launch(void* const* d_in, const int* in_sizes, int n_in,
                              void* d_out, int out_size, void* d_ws, size_t ws_size,
                              hipStream_t stream) {
    const float* x  = (const float*)d_in[0];
    const int*   ei = (const int*)d_in[1];
    const float* ew = (const float*)d_in[2];
    const float* W1 = (const float*)d_in[3];
    const float* b1 = (const float*)d_in[4];
    const float* W2 = (const float*)d_in[5];
    const float* b2 = (const float*)d_in[6];
    const float* Wc = (const float*)d_in[7];
    const float* bc = (const float*)d_in[8];
    float* out = (float*)d_out;

    const int E = in_sizes[1] / 2;
    const int F = 512, D = 256;
    const int N = in_sizes[0] / F;
    const int* row = ei;
    const int* col = ei + E;

    char* ws = (char*)d_ws;
    size_t p = 0;
    auto alloc = [&](size_t bytes) -> char* {
        char* r = ws + p;
        p += (bytes + 255) & ~(size_t)255;
        return r;
    };
    float* deg   = (float*)alloc((size_t)N * 4);        // becomes dinv in place
    int*   off   = (int*)alloc((size_t)(N + 1) * 4);
    int*   cnt   = (int*)alloc((size_t)N * 4);
    int*   cur   = (int*)alloc((size_t)N * 4);
    int*   csr_r = (int*)alloc((size_t)E * 4);
    float* csr_n = (float*)alloc((size_t)E * 4);
    float* h     = (float*)alloc((size_t)N * D * 4);
    float* agg   = (float*)alloc((size_t)N * D * 4);
    _Float16* Bp1h = (_Float16*)alloc((size_t)F * D * 2);
    _Float16* Bp1l = (_Float16*)alloc((size_t)F * D * 2);
    _Float16* Bp2h = (_Float16*)alloc((size_t)D * D * 2);
    _Float16* Bp2l = (_Float16*)alloc((size_t)D * D * 2);
    (void)ws_size;

    // graph norm + CSR build
    init_kernel<<<(N + 255) / 256, 256, 0, stream>>>(deg, cnt, cur, N);
    deg_cnt_kernel<<<(E + 255) / 256, 256, 0, stream>>>(col, ew, deg, cnt, E);
    dinv_kernel<<<(N + 255) / 256, 256, 0, stream>>>(deg, N);
    scan_kernel<<<1, 1024, 0, stream>>>(cnt, off, N);
    fill_kernel<<<(E + 255) / 256, 256, 0, stream>>>(row, col, ew, deg, off, cur, csr_r, csr_n, E);

    // pack weights (hi/lo f16 k-panels)
    prep_b_kernel<<<(F * D + 255) / 256, 256, 0, stream>>>(W1, Bp1h, Bp1l, F);
    prep_b_kernel<<<(D * D + 255) / 256, 256, 0, stream>>>(W2, Bp2h, Bp2l, D);

    int gm = (N + 63) / 64;
    // layer 1: h = x @ W1 ; agg = ReLU(A_hat h + b1)
    gemm_split_kernel<<<gm, 256, 0, stream>>>(x, Bp1h, Bp1l, h, N, F);
    agg_kernel<<<(N + 3) / 4, 256, 0, stream>>>(h, csr_r, csr_n, off, deg, b1, agg, N, 1);
    // layer 2: h = agg @ W2 ; agg = ReLU(A_hat h + b2)
    gemm_split_kernel<<<gm, 256, 0, stream>>>(agg, Bp2h, Bp2l, h, N, D);
    agg_kernel<<<(N + 3) / 4, 256, 0, stream>>>(h, csr_r, csr_n, off, deg, b2, agg, N, 1);
    // classifier
    cls_kernel<<<(N + 3) / 4, 256, 0, stream>>>(agg, Wc, bc, out, N);
}

// Round 6
// 2185.048 us; speedup vs baseline: 1.1561x; 1.0896x over previous
//
#include <hip/hip_runtime.h>

// GCN forward: 2x (split-f16 MFMA GEMM -> D^-1/2 A D^-1/2 aggregate -> +b -> ReLU) -> linear head.
// GEMM v2: B (hi+lo f16 k-panels) staged per 32-k chunk into LDS, shared by 4 waves;
// each wave computes 32 rows x 256 cols (2 m-frags), so one B fragment feeds 6 MFMAs.

typedef __attribute__((ext_vector_type(8))) _Float16 f16x8;
typedef __attribute__((ext_vector_type(4))) float f32x4;

__global__ __launch_bounds__(256) void init_kernel(float* deg, int* cnt, int* cur, int N) {
    int i = blockIdx.x * 256 + threadIdx.x;
    if (i < N) { deg[i] = 1.0f; cnt[i] = 0; cur[i] = 0; }  // deg starts at 1 (self-loop weight)
}

__global__ __launch_bounds__(256) void deg_cnt_kernel(const int* __restrict__ col,
                                                      const float* __restrict__ w,
                                                      float* deg, int* cnt, int E) {
    int e = blockIdx.x * 256 + threadIdx.x;
    if (e < E) {
        int c = col[e];
        atomicAdd(&deg[c], w[e]);
        atomicAdd(&cnt[c], 1);
    }
}

__global__ __launch_bounds__(256) void dinv_kernel(float* deg, int N) {
    int i = blockIdx.x * 256 + threadIdx.x;
    if (i < N) deg[i] = rsqrtf(deg[i]);  // deg >= 1 always (self-loop)
}

// Single-block coarsened exclusive scan of cnt[0..N) -> off[0..N]
__global__ __launch_bounds__(1024) void scan_kernel(const int* __restrict__ cnt,
                                                    int* __restrict__ off, int N) {
    __shared__ int sm[1024];
    int t = threadIdx.x;
    int chunk = (N + 1023) >> 10;
    int b = t * chunk;
    int e = min(b + chunk, N);
    int s = 0;
    for (int i = b; i < e; i++) s += cnt[i];
    sm[t] = s;
    __syncthreads();
#pragma unroll
    for (int d = 1; d < 1024; d <<= 1) {
        int v = (t >= d) ? sm[t - d] : 0;
        __syncthreads();
        sm[t] += v;
        __syncthreads();
    }
    int run = sm[t] - s;  // exclusive prefix of this thread's chunk
    for (int i = b; i < e; i++) { off[i] = run; run += cnt[i]; }
    if (t == 1023) off[N] = sm[1023];
}

__global__ __launch_bounds__(256) void fill_kernel(const int* __restrict__ row,
                                                   const int* __restrict__ col,
                                                   const float* __restrict__ w,
                                                   const float* __restrict__ dinv,
                                                   const int* __restrict__ off, int* cur,
                                                   int* __restrict__ csr_r,
                                                   float* __restrict__ csr_n, int E) {
    int e = blockIdx.x * 256 + threadIdx.x;
    if (e >= E) return;
    int r = row[e], c = col[e];
    int pos = off[c] + atomicAdd(&cur[c], 1);
    csr_r[pos] = r;
    csr_n[pos] = dinv[r] * w[e] * dinv[c];
}

// Pack B [K][256] f32 -> hi/lo f16 k-panels: Bp[k>>3][n][k&7]
__global__ __launch_bounds__(256) void prep_b_kernel(const float* __restrict__ B,
                                                     _Float16* __restrict__ Bph,
                                                     _Float16* __restrict__ Bpl, int K) {
    int e = blockIdx.x * 256 + threadIdx.x;
    if (e >= K * 256) return;
    int k = e >> 8, n = e & 255;
    float v = B[e];
    _Float16 h = (_Float16)v;
    _Float16 lo = (_Float16)(v - (float)h);
    size_t idx = ((((size_t)(k >> 3)) * 256 + n) << 3) | (k & 7);
    Bph[idx] = h;
    Bpl[idx] = lo;
}

// C[M,256] = A[M,K] @ B[K,256] via split-f16 MFMA (16x16x32).
// grid.x = ceil(M/128); 4 waves/block, each wave owns 32 rows x all 256 cols.
// B staged per 32-k chunk in LDS (hi 16KB + lo 16KB), shared by all 4 waves.
__global__ __launch_bounds__(256) void gemm_split_kernel(const float* __restrict__ A,
                                                         const _Float16* __restrict__ Bph,
                                                         const _Float16* __restrict__ Bpl,
                                                         float* __restrict__ C,
                                                         int M, int K) {
    __shared__ f16x8 sB[2][1024];  // [hi/lo][kb*256 + n], kb = 8-k group 0..3, n = col
    int t = threadIdx.x;
    int w = t >> 6, l = t & 63;
    int lr = l & 15;   // row-within-16 (A), col-within-16 (B/C)
    int lg = l >> 4;   // k-group 0..3 (8 k each)
    int m0 = blockIdx.x * 128 + w * 32;

    int ar0 = m0 + lr;       if (ar0 >= M) ar0 = M - 1;  // clamp; stores guarded below
    int ar1 = m0 + 16 + lr;  if (ar1 >= M) ar1 = M - 1;
    const float* Ap0 = A + (size_t)ar0 * K + lg * 8;
    const float* Ap1 = A + (size_t)ar1 * K + lg * 8;

    f32x4 acc0[16], acc1[16];
#pragma unroll
    for (int i = 0; i < 16; i++) { acc0[i] = (f32x4)0.0f; acc1[i] = (f32x4)0.0f; }

    const f16x8* GHbase = (const f16x8*)Bph;
    const f16x8* GLbase = (const f16x8*)Bpl;

    for (int k0 = 0; k0 < K; k0 += 32) {
        // --- stage B chunk (32 k x 256 n, hi+lo) into LDS, coalesced ---
        const f16x8* GH = GHbase + ((size_t)(k0 >> 3)) * 256;
        const f16x8* GL = GLbase + ((size_t)(k0 >> 3)) * 256;
        __syncthreads();  // protect previous chunk's reads
#pragma unroll
        for (int u = 0; u < 4; u++) {
            int idx = u * 256 + t;
            sB[0][idx] = GH[idx];
            sB[1][idx] = GL[idx];
        }
        __syncthreads();

        // --- A fragments for both 16-row groups, split hi/lo ---
        f16x8 ah0, al0, ah1, al1;
        {
            f32x4 a0 = *(const f32x4*)(Ap0 + k0);
            f32x4 a1 = *(const f32x4*)(Ap0 + k0 + 4);
#pragma unroll
            for (int j = 0; j < 4; j++) {
                float v = a0[j]; _Float16 hi = (_Float16)v;
                ah0[j] = hi; al0[j] = (_Float16)(v - (float)hi);
                float v2 = a1[j]; _Float16 hi2 = (_Float16)v2;
                ah0[j + 4] = hi2; al0[j + 4] = (_Float16)(v2 - (float)hi2);
            }
            f32x4 b0 = *(const f32x4*)(Ap1 + k0);
            f32x4 b1 = *(const f32x4*)(Ap1 + k0 + 4);
#pragma unroll
            for (int j = 0; j < 4; j++) {
                float v = b0[j]; _Float16 hi = (_Float16)v;
                ah1[j] = hi; al1[j] = (_Float16)(v - (float)hi);
                float v2 = b1[j]; _Float16 hi2 = (_Float16)v2;
                ah1[j + 4] = hi2; al1[j + 4] = (_Float16)(v2 - (float)hi2);
            }
        }

        // --- 16 col-fragments x (2 m-reps x 3 split products) ---
#pragma unroll
        for (int nf = 0; nf < 16; nf++) {
            f16x8 bh = sB[0][lg * 256 + nf * 16 + lr];
            f16x8 bl = sB[1][lg * 256 + nf * 16 + lr];
            acc0[nf] = __builtin_amdgcn_mfma_f32_16x16x32_f16(ah0, bh, acc0[nf], 0, 0, 0);
            acc0[nf] = __builtin_amdgcn_mfma_f32_16x16x32_f16(al0, bh, acc0[nf], 0, 0, 0);
            acc0[nf] = __builtin_amdgcn_mfma_f32_16x16x32_f16(ah0, bl, acc0[nf], 0, 0, 0);
            acc1[nf] = __builtin_amdgcn_mfma_f32_16x16x32_f16(ah1, bh, acc1[nf], 0, 0, 0);
            acc1[nf] = __builtin_amdgcn_mfma_f32_16x16x32_f16(al1, bh, acc1[nf], 0, 0, 0);
            acc1[nf] = __builtin_amdgcn_mfma_f32_16x16x32_f16(ah1, bl, acc1[nf], 0, 0, 0);
        }
    }

    // C/D layout (m89-verified): col = lane&15 (+16*nf), row = (lane>>4)*4 + reg
#pragma unroll
    for (int nf = 0; nf < 16; nf++) {
#pragma unroll
        for (int r = 0; r < 4; r++) {
            int row0 = m0 + lg * 4 + r;
            if (row0 < M) C[(size_t)row0 * 256 + nf * 16 + lr] = acc0[nf][r];
            int row1 = m0 + 16 + lg * 4 + r;
            if (row1 < M) C[(size_t)row1 * 256 + nf * 16 + lr] = acc1[nf][r];
        }
    }
}

// One wave per node: out[n] = ReLU( sum_e norm_e * h[row_e] + dinv[n]^2 * h[n] + b )
// D = 256 floats per row; lane handles 4 (float4).
__global__ __launch_bounds__(256) void agg_kernel(const float* __restrict__ h,
                                                  const int* __restrict__ csr_r,
                                                  const float* __restrict__ csr_n,
                                                  const int* __restrict__ off,
                                                  const float* __restrict__ dinv,
                                                  const float* __restrict__ bias,
                                                  float* __restrict__ out, int N, int relu) {
    int lane = threadIdx.x & 63;
    int n = blockIdx.x * 4 + (threadIdx.x >> 6);
    if (n >= N) return;
    n = __builtin_amdgcn_readfirstlane(n);
    int start = off[n], end = off[n + 1];
    float d = dinv[n];
    const float4* hv = (const float4*)h;
    float4 self = hv[(size_t)n * 64 + lane];
    float sw = d * d;
    float ax = sw * self.x, ay = sw * self.y, az = sw * self.z, aw = sw * self.w;
    int j = start;
    for (; j + 4 <= end; j += 4) {
        int r0 = csr_r[j], r1 = csr_r[j + 1], r2 = csr_r[j + 2], r3 = csr_r[j + 3];
        float n0 = csr_n[j], n1 = csr_n[j + 1], n2 = csr_n[j + 2], n3 = csr_n[j + 3];
        float4 h0 = hv[(size_t)r0 * 64 + lane];
        float4 h1 = hv[(size_t)r1 * 64 + lane];
        float4 h2 = hv[(size_t)r2 * 64 + lane];
        float4 h3 = hv[(size_t)r3 * 64 + lane];
        ax += n0 * h0.x + n1 * h1.x + n2 * h2.x + n3 * h3.x;
        ay += n0 * h0.y + n1 * h1.y + n2 * h2.y + n3 * h3.y;
        az += n0 * h0.z + n1 * h1.z + n2 * h2.z + n3 * h3.z;
        aw += n0 * h0.w + n1 * h1.w + n2 * h2.w + n3 * h3.w;
    }
    for (; j < end; j++) {
        int r = csr_r[j];
        float nm = csr_n[j];
        float4 hr = hv[(size_t)r * 64 + lane];
        ax += nm * hr.x; ay += nm * hr.y; az += nm * hr.z; aw += nm * hr.w;
    }
    float4 b = ((const float4*)bias)[lane];
    ax += b.x; ay += b.y; az += b.z; aw += b.w;
    if (relu) {
        ax = fmaxf(ax, 0.f); ay = fmaxf(ay, 0.f);
        az = fmaxf(az, 0.f); aw = fmaxf(aw, 0.f);
    }
    ((float4*)out)[(size_t)n * 64 + lane] = make_float4(ax, ay, az, aw);
}

// out[n,c] = h[n,:] @ Wc[:,c] + bc[c], c < 10. One wave per node, shuffle reduce.
__global__ __launch_bounds__(256) void cls_kernel(const float* __restrict__ h,
                                                  const float* __restrict__ Wc,
                                                  const float* __restrict__ bc,
                                                  float* __restrict__ out, int N) {
    __shared__ float Ws[256 * 10];
    for (int i = threadIdx.x; i < 2560; i += 256) Ws[i] = Wc[i];
    __syncthreads();
    int lane = threadIdx.x & 63;
    int n = blockIdx.x * 4 + (threadIdx.x >> 6);
    if (n >= N) return;
    float4 hv4 = ((const float4*)h)[(size_t)n * 64 + lane];
    float s[10];
#pragma unroll
    for (int c = 0; c < 10; c++) {
        float v = hv4.x * Ws[(4 * lane + 0) * 10 + c] + hv4.y * Ws[(4 * lane + 1) * 10 + c] +
                  hv4.z * Ws[(4 * lane + 2) * 10 + c] + hv4.w * Ws[(4 * lane + 3) * 10 + c];
#pragma unroll
        for (int m = 32; m; m >>= 1) v += __shfl_xor(v, m, 64);
        s[c] = v;
    }
    float outv = 0.0f;
#pragma unroll
    for (int c = 0; c < 10; c++)
        if (lane == c) outv = s[c] + bc[c];
    if (lane < 10) out[(size_t)n * 10 + lane] = outv;
}

extern "C" void kernel_launch(void* const* d_in, const int* in_sizes, int n_in,
                              void* d_out, int out_size, void* d_ws, size_t ws_size,
                              hipStream_t stream) {
    const float* x  = (const float*)d_in[0];
    const int*   ei = (const int*)d_in[1];
    const float* ew = (const float*)d_in[2];
    const float* W1 = (const float*)d_in[3];
    const float* b1 = (const float*)d_in[4];
    const float* W2 = (const float*)d_in[5];
    const float* b2 = (const float*)d_in[6];
    const float* Wc = (const float*)d_in[7];
    const float* bc = (const float*)d_in[8];
    float* out = (float*)d_out;

    const int E = in_sizes[1] / 2;
    const int F = 512, D = 256;
    const int N = in_sizes[0] / F;
    const int* row = ei;
    const int* col = ei + E;

    char* ws = (char*)d_ws;
    size_t p = 0;
    auto alloc = [&](size_t bytes) -> char* {
        char* r = ws + p;
        p += (bytes + 255) & ~(size_t)255;
        return r;
    };
    float* deg   = (float*)alloc((size_t)N * 4);        // becomes dinv in place
    int*   off   = (int*)alloc((size_t)(N + 1) * 4);
    int*   cnt   = (int*)alloc((size_t)N * 4);
    int*   cur   = (int*)alloc((size_t)N * 4);
    int*   csr_r = (int*)alloc((size_t)E * 4);
    float* csr_n = (float*)alloc((size_t)E * 4);
    float* h     = (float*)alloc((size_t)N * D * 4);
    float* agg   = (float*)alloc((size_t)N * D * 4);
    _Float16* Bp1h = (_Float16*)alloc((size_t)F * D * 2);
    _Float16* Bp1l = (_Float16*)alloc((size_t)F * D * 2);
    _Float16* Bp2h = (_Float16*)alloc((size_t)D * D * 2);
    _Float16* Bp2l = (_Float16*)alloc((size_t)D * D * 2);
    (void)ws_size;

    // graph norm + CSR build
    init_kernel<<<(N + 255) / 256, 256, 0, stream>>>(deg, cnt, cur, N);
    deg_cnt_kernel<<<(E + 255) / 256, 256, 0, stream>>>(col, ew, deg, cnt, E);
    dinv_kernel<<<(N + 255) / 256, 256, 0, stream>>>(deg, N);
    scan_kernel<<<1, 1024, 0, stream>>>(cnt, off, N);
    fill_kernel<<<(E + 255) / 256, 256, 0, stream>>>(row, col, ew, deg, off, cur, csr_r, csr_n, E);

    // pack weights (hi/lo f16 k-panels)
    prep_b_kernel<<<(F * D + 255) / 256, 256, 0, stream>>>(W1, Bp1h, Bp1l, F);
    prep_b_kernel<<<(D * D + 255) / 256, 256, 0, stream>>>(W2, Bp2h, Bp2l, D);

    int gm = (N + 127) / 128;
    // layer 1: h = x @ W1 ; agg = ReLU(A_hat h + b1)
    gemm_split_kernel<<<gm, 256, 0, stream>>>(x, Bp1h, Bp1l, h, N, F);
    agg_kernel<<<(N + 3) / 4, 256, 0, stream>>>(h, csr_r, csr_n, off, deg, b1, agg, N, 1);
    // layer 2: h = agg @ W2 ; agg = ReLU(A_hat h + b2)
    gemm_split_kernel<<<gm, 256, 0, stream>>>(agg, Bp2h, Bp2l, h, N, D);
    agg_kernel<<<(N + 3) / 4, 256, 0, stream>>>(h, csr_r, csr_n, off, deg, b2, agg, N, 1);
    // classifier
    cls_kernel<<<(N + 3) / 4, 256, 0, stream>>>(agg, Wc, bc, out, N);
}